// Round 4
// baseline (185.241 us; speedup 1.0000x reference)
//
#include <hip/hip_runtime.h>
#include <hip/hip_bf16.h>

// GAT on fully-connected graph, N=4096, F=D=64, H=4, OUT=2.
// e[t,s,h]=lrelu(dst_t+src_s); exp(lrelu) factors per branch:
//   src > -dst : weight = e^{dst} * e^{src}
//   src <= -dst: weight = e^{0.2 dst} * e^{0.2 src}
// Sort sources per head; suffix sums (pos branch) + prefix sums (neg branch)
// of weight*h2 over sorted order; each target = rank(-dst) + two 65-float rows.

#define N 4096
#define D 64
#define H 4
#define HD 256
#define TS 66           // row stride of tables (65 cols: 64 dims + weight col)

__device__ __forceinline__ void fma4(float4& a, float s, const float4& b) {
  a.x = fmaf(s, b.x, a.x); a.y = fmaf(s, b.y, a.y);
  a.z = fmaf(s, b.z, a.z); a.w = fmaf(s, b.w, a.w);
}

// ---------- shared proj body: 8 rows/block from LDS xs, W from global ----------
__device__ __forceinline__ void proj_body(const float (*xs)[64], int r0,
    const float* __restrict__ W, const float* __restrict__ asrc,
    const float* __restrict__ adst, float* __restrict__ h2,
    float* __restrict__ ssrc, float* __restrict__ sdst) {
  int tid = threadIdx.x;
  int lane6 = tid & 63;
  int c0 = lane6 * 4;              // 4 output cols per thread
  int hh = lane6 >> 4;             // head of this 16-lane group
  int rbase = (tid >> 6) * 2;      // 2 rows per thread
  float4 acc0 = make_float4(0.f, 0.f, 0.f, 0.f);
  float4 acc1 = make_float4(0.f, 0.f, 0.f, 0.f);
#pragma unroll
  for (int kq = 0; kq < 16; ++kq) {
    const float* Wk = W + kq * 4 * 256 + c0;
    float4 w0 = *(const float4*)(Wk);
    float4 w1 = *(const float4*)(Wk + 256);
    float4 w2 = *(const float4*)(Wk + 512);
    float4 w3 = *(const float4*)(Wk + 768);
    float4 x0 = *(const float4*)(&xs[rbase][kq * 4]);
    float4 x1 = *(const float4*)(&xs[rbase + 1][kq * 4]);
    fma4(acc0, x0.x, w0); fma4(acc0, x0.y, w1); fma4(acc0, x0.z, w2); fma4(acc0, x0.w, w3);
    fma4(acc1, x1.x, w0); fma4(acc1, x1.y, w1); fma4(acc1, x1.z, w2); fma4(acc1, x1.w, w3);
  }
  float4 av = *(const float4*)(asrc + c0);
  float4 bv = *(const float4*)(adst + c0);
#pragma unroll
  for (int r = 0; r < 2; ++r) {
    float4 a = (r == 0) ? acc0 : acc1;
    int row = r0 + rbase + r;
    *(float4*)(h2 + row * 256 + c0) = a;
    float ps = a.x * av.x + a.y * av.y + a.z * av.z + a.w * av.w;
    float pd = a.x * bv.x + a.y * bv.y + a.z * bv.z + a.w * bv.w;
#pragma unroll
    for (int off = 8; off > 0; off >>= 1) {
      ps += __shfl_down(ps, off);
      pd += __shfl_down(pd, off);
    }
    if ((lane6 & 15) == 0) {
      ssrc[hh * N + row] = ps;
      sdst[hh * N + row] = pd;
    }
  }
}

// ---------- layer1: encoder (relu(x@Wenc+benc)) fused with proj ----------
__global__ __launch_bounds__(256) void k_encproj(const float* __restrict__ x,
    const float* __restrict__ Wenc, const float* __restrict__ benc,
    const float* __restrict__ W, const float* __restrict__ asrc,
    const float* __restrict__ adst, float* __restrict__ h2,
    float* __restrict__ ssrc, float* __restrict__ sdst) {
  __shared__ float xs[8][64];
  int tid = threadIdx.x;
  int r0 = blockIdx.x * 8;
  {
    int row = tid >> 5;            // 0..7
    int c = (tid & 31) * 2;        // 0..62
    const float* xr = x + (r0 + row) * 64;
    float a0 = benc[c], a1 = benc[c + 1];
#pragma unroll
    for (int k = 0; k < 64; ++k) {
      float xv = xr[k];
      float2 w = *(const float2*)(Wenc + k * 64 + c);
      a0 = fmaf(xv, w.x, a0);
      a1 = fmaf(xv, w.y, a1);
    }
    xs[row][c] = fmaxf(a0, 0.f);
    xs[row][c + 1] = fmaxf(a1, 0.f);
  }
  __syncthreads();
  proj_body(xs, r0, W, asrc, adst, h2, ssrc, sdst);
}

// ---------- layer2 proj: stage hin rows then proj ----------
__global__ __launch_bounds__(256) void k_proj(const float* __restrict__ hin,
    const float* __restrict__ W, const float* __restrict__ asrc,
    const float* __restrict__ adst, float* __restrict__ h2,
    float* __restrict__ ssrc, float* __restrict__ sdst) {
  __shared__ float xs[8][64];
  int tid = threadIdx.x;
  int r0 = blockIdx.x * 8;
  if (tid < 128) ((float4*)xs)[tid] = ((const float4*)(hin + r0 * 64))[tid];
  __syncthreads();
  proj_body(xs, r0, W, asrc, adst, h2, ssrc, sdst);
}

// ---------- rank: one kernel; wave = j-quarter, lane = i; key-compare ----------
__device__ __forceinline__ unsigned fkeyu(unsigned b) {
  return b ^ ((unsigned)((int)b >> 31) | 0x80000000u);   // monotonic float->uint
}
__device__ __forceinline__ float fkeyinv(unsigned k) {
  int b = (k & 0x80000000u) ? (int)(k ^ 0x80000000u) : ~(int)k;
  return __int_as_float(b);
}

__global__ __launch_bounds__(256) void k_rank(const float* __restrict__ ssrc,
                                              float* __restrict__ srtv, int* __restrict__ srti,
                                              float* __restrict__ wA, float* __restrict__ wB) {
  __shared__ int rpart[4][64];
  __shared__ unsigned wmaxk[4];
  __shared__ float vv[64];
  int b = blockIdx.x;
  int h = b >> 6, g = b & 63;
  int tid = threadIdx.x;
  int lane = tid & 63;
  int jq = __builtin_amdgcn_readfirstlane(tid >> 6);   // wave-uniform quarter
  int i = g * 64 + lane;
  float vi = ssrc[h * N + i];
  unsigned ki = fkeyu(__float_as_uint(vi));
  unsigned long long Ki = ((unsigned long long)ki << 32) | (unsigned)i;
  const uint4* src = (const uint4*)(ssrc + h * N) + jq * 256;
  int jb0 = jq * 1024;
  int rank = 0;
  unsigned mxk = 0u;
#pragma unroll 8
  for (int t = 0; t < 256; ++t) {
    uint4 q = src[t];
    unsigned k0 = fkeyu(q.x), k1 = fkeyu(q.y), k2 = fkeyu(q.z), k3 = fkeyu(q.w);
    int jb = jb0 + t * 4;
    rank += (((unsigned long long)k0 << 32) | (unsigned)(jb + 0)) < Ki;
    rank += (((unsigned long long)k1 << 32) | (unsigned)(jb + 1)) < Ki;
    rank += (((unsigned long long)k2 << 32) | (unsigned)(jb + 2)) < Ki;
    rank += (((unsigned long long)k3 << 32) | (unsigned)(jb + 3)) < Ki;
    mxk = max(mxk, max(max(k0, k1), max(k2, k3)));
  }
  rpart[jq][lane] = rank;
  if (lane == 0) wmaxk[jq] = mxk;
  if (jq == 0) vv[lane] = vi;
  __syncthreads();
  if (tid < 64) {
    int rk = rpart[0][tid] + rpart[1][tid] + rpart[2][tid] + rpart[3][tid];
    unsigned mk = max(max(wmaxk[0], wmaxk[1]), max(wmaxk[2], wmaxk[3]));
    float m1 = fkeyinv(mk);
    float v = vv[tid];
    int idx = h * N + rk;
    srtv[idx] = v;
    srti[idx] = g * 64 + tid;
    wA[idx] = expf(v - m1);
    wB[idx] = expf(0.2f * (v - m1));
  }
}

// ---------- S1: per-chunk totals ----------
__global__ __launch_bounds__(128) void k_s1(const float* __restrict__ h2,
                                            const int* __restrict__ srti,
                                            const float* __restrict__ wA, const float* __restrict__ wB,
                                            float* __restrict__ TA, float* __restrict__ TB) {
    int h = blockIdx.x >> 6, c = blockIdx.x & 63, col = threadIdx.x;
    __shared__ int pj[64];
    __shared__ float wa[64], wb[64];
    int j0 = c * 64;
    if (col < 64) {
        int j = j0 + col;
        pj[col] = srti[h * N + j];
        wa[col] = wA[h * N + j];
        wb[col] = wB[h * N + j];
    }
    __syncthreads();
    if (col >= 65) return;
    float accA = 0.f, accB = 0.f;
#pragma unroll 8
    for (int j = 0; j < 64; ++j) {
        float val = (col < 64) ? h2[pj[j] * HD + h * 64 + col] : 1.0f;
        accA = fmaf(wa[j], val, accA);
        accB = fmaf(wb[j], val, accB);
    }
    TA[(h * 64 + c) * TS + col] = accA;
    TB[(h * 64 + c) * TS + col] = accB;
}

// ---------- S3: self-computed offsets + full suffix/prefix tables ----------
__global__ __launch_bounds__(128) void k_s3(const float* __restrict__ h2,
                                            const int* __restrict__ srti,
                                            const float* __restrict__ wA, const float* __restrict__ wB,
                                            const float* __restrict__ TA, const float* __restrict__ TB,
                                            float* __restrict__ SA, float* __restrict__ PB) {
    int h = blockIdx.x >> 6, c = blockIdx.x & 63, col = threadIdx.x;
    __shared__ int pj[64];
    __shared__ float wa[64], wb[64];
    int j0 = c * 64;
    if (col < 64) {
        pj[col] = srti[h * N + j0 + col];
        wa[col] = wA[h * N + j0 + col];
        wb[col] = wB[h * N + j0 + col];
    }
    __syncthreads();
    if (col >= 65) return;
    float offA = 0.f, offB = 0.f;
    for (int cc = c + 1; cc < 64; ++cc) offA += TA[(h * 64 + cc) * TS + col];
    for (int cc = 0; cc < c; ++cc)      offB += TB[(h * 64 + cc) * TS + col];
    float v[64];
#pragma unroll
    for (int j = 0; j < 64; ++j)
        v[j] = (col < 64) ? h2[pj[j] * HD + h * 64 + col] : 1.0f;
    float acc = offA;
#pragma unroll
    for (int j = 63; j >= 0; --j) {  // SA[i] = sum_{j>=i} wA_j * v_j
        acc = fmaf(wa[j], v[j], acc);
        SA[(size_t)(h * (N + 1) + j0 + j) * TS + col] = acc;
    }
    acc = offB;
#pragma unroll
    for (int j = 0; j < 64; ++j) {   // PB[i] = sum_{j<i} wB_j * v_j
        acc = fmaf(wb[j], v[j], acc);
        PB[(size_t)(h * (N + 1) + j0 + j + 1) * TS + col] = acc;
    }
    if (c == 63) SA[(size_t)(h * (N + 1) + N) * TS + col] = 0.f;
    if (c == 0)  PB[(size_t)(h * (N + 1) + 0) * TS + col] = 0.f;
}

// ---------- target: blend tables per (t,h); MODE1 fuses output heads ----------
template <int MODE>
__global__ __launch_bounds__(256) void k_target_t(const float* __restrict__ sdst,
                                                  const float* __restrict__ srtv,
                                                  const float* __restrict__ SA,
                                                  const float* __restrict__ PB,
                                                  const float* __restrict__ bias,
                                                  float* __restrict__ hout,
                                                  const float* __restrict__ Wact,
                                                  const float* __restrict__ bact,
                                                  const float* __restrict__ Wcri,
                                                  const float* __restrict__ bcri,
                                                  float* __restrict__ out) {
    __shared__ float bnd[4][64];
    int tid = threadIdx.x;
    { int hh = tid >> 6, l = tid & 63; bnd[hh][l] = srtv[hh * N + l * 64]; }
    __syncthreads();
    int t = blockIdx.x * 4 + (tid >> 6);
    int lane = tid & 63;
    float acc = 0.f;
#pragma unroll
    for (int h = 0; h < H; ++h) {
        const float* sv = srtv + h * N;
        float dst = sdst[h * N + t];
        float thr = -dst;
        float m1 = sv[N - 1];
        unsigned long long b1 = __ballot(bnd[h][lane] <= thr);
        int c1 = __popcll(b1);
        int seg = c1 > 0 ? c1 - 1 : 0;
        unsigned long long b2 = __ballot(sv[seg * 64 + lane] <= thr);
        int k = seg * 64 + __popcll(b2);
        float u = dst + m1;
        float g = fmaxf(u, 0.2f * u);          // keeps both exps <= 1
        float wAt = expf(u - g);
        float wBt = expf(0.2f * u - g);
        const float* sa = SA + (size_t)(h * (N + 1) + k) * TS;
        const float* pb = PB + (size_t)(h * (N + 1) + k) * TS;
        float num = wAt * sa[lane] + wBt * pb[lane];
        float den = wAt * sa[64] + wBt * pb[64];
        acc += num / den;
    }
    float hv = fmaxf(acc * 0.25f + bias[lane], 0.f);
    if constexpr (MODE == 0) {
        hout[t * 64 + lane] = hv;
    } else {
        float p0 = hv * Wact[lane * 2 + 0];
        float p1 = hv * Wact[lane * 2 + 1];
        float p2 = hv * Wcri[lane];
#pragma unroll
        for (int off = 32; off > 0; off >>= 1) {
            p0 += __shfl_down(p0, off);
            p1 += __shfl_down(p1, off);
            p2 += __shfl_down(p2, off);
        }
        if (lane == 0) {
            float l0 = fminf(fmaxf(p0 + bact[0], -5.f), 5.f);
            float l1 = fminf(fmaxf(p1 + bact[1], -5.f), 5.f);
            out[t * 2 + 0] = l0;
            out[t * 2 + 1] = fabsf(l1);
            out[2 * N + t] = p2 + bcri[0];
        }
    }
}

extern "C" void kernel_launch(void* const* d_in, const int* in_sizes, int n_in,
                              void* d_out, int out_size, void* d_ws, size_t ws_size,
                              hipStream_t stream) {
    (void)in_sizes; (void)n_in; (void)out_size; (void)ws_size;
    const float* x     = (const float*)d_in[0];
    const float* W_enc = (const float*)d_in[1];
    const float* b_enc = (const float*)d_in[2];
    const float* W1    = (const float*)d_in[3];
    const float* as1   = (const float*)d_in[4];
    const float* ad1   = (const float*)d_in[5];
    const float* b1    = (const float*)d_in[6];
    const float* W2    = (const float*)d_in[7];
    const float* as2   = (const float*)d_in[8];
    const float* ad2   = (const float*)d_in[9];
    const float* b2    = (const float*)d_in[10];
    const float* W_act = (const float*)d_in[11];
    const float* b_act = (const float*)d_in[12];
    const float* W_cri = (const float*)d_in[13];
    const float* b_cri = (const float*)d_in[14];
    float* out = (float*)d_out;

    float* p = (float*)d_ws;
    float* h2   = p; p += N * HD;
    float* hA   = p; p += N * D;
    float* ssrc = p; p += H * N;
    float* sdst = p; p += H * N;
    float* srtv = p; p += H * N;
    int*   srti = (int*)p; p += H * N;
    float* wA   = p; p += H * N;
    float* wB   = p; p += H * N;
    float* TA   = p; p += H * 64 * TS;
    float* TB   = p; p += H * 64 * TS;
    float* SA   = p; p += (size_t)H * (N + 1) * TS;
    float* PB   = p; p += (size_t)H * (N + 1) * TS;

    // layer 1 (encoder fused into proj)
    k_encproj<<<N / 8, 256, 0, stream>>>(x, W_enc, b_enc, W1, as1, ad1, h2, ssrc, sdst);
    k_rank<<<H * 64, 256, 0, stream>>>(ssrc, srtv, srti, wA, wB);
    k_s1<<<H * 64, 128, 0, stream>>>(h2, srti, wA, wB, TA, TB);
    k_s3<<<H * 64, 128, 0, stream>>>(h2, srti, wA, wB, TA, TB, SA, PB);
    k_target_t<0><<<N / 4, 256, 0, stream>>>(sdst, srtv, SA, PB, b1, hA,
                                             nullptr, nullptr, nullptr, nullptr, nullptr);

    // layer 2 (heads fused into target)
    k_proj<<<N / 8, 256, 0, stream>>>(hA, W2, as2, ad2, h2, ssrc, sdst);
    k_rank<<<H * 64, 256, 0, stream>>>(ssrc, srtv, srti, wA, wB);
    k_s1<<<H * 64, 128, 0, stream>>>(h2, srti, wA, wB, TA, TB);
    k_s3<<<H * 64, 128, 0, stream>>>(h2, srti, wA, wB, TA, TB, SA, PB);
    k_target_t<1><<<N / 4, 256, 0, stream>>>(sdst, srtv, SA, PB, b2, nullptr,
                                             W_act, b_act, W_cri, b_cri, out);
}

// Round 5
// 128.480 us; speedup vs baseline: 1.4418x; 1.4418x over previous
//
#include <hip/hip_runtime.h>
#include <hip/hip_bf16.h>

// GAT on fully-connected graph, N=4096, F=D=64, H=4, OUT=2.
// e[t,s,h]=lrelu(dst_t+src_s); exp(lrelu) factors per branch:
//   src > -dst : weight = e^{dst} * e^{src}
//   src <= -dst: weight = e^{0.2 dst} * e^{0.2 src}
// Sort sources per head; suffix sums (pos branch) + prefix sums (neg branch)
// of weight*h2 over sorted order; each target = rank(-dst) + two 65-float rows.

#define N 4096
#define D 64
#define H 4
#define HD 256
#define TS 66           // row stride of tables (65 cols: 64 dims + weight col)
#define RCHUNK 16       // j-chunks for rank computation
#define RJ (N / RCHUNK) // 256

__device__ __forceinline__ void fma4(float4& a, float s, const float4& b) {
  a.x = fmaf(s, b.x, a.x); a.y = fmaf(s, b.y, a.y);
  a.z = fmaf(s, b.z, a.z); a.w = fmaf(s, b.w, a.w);
}

// ---------- shared proj body: 8 rows/block from LDS xs, W from global ----------
__device__ __forceinline__ void proj_body(const float (*xs)[64], int r0,
    const float* __restrict__ W, const float* __restrict__ asrc,
    const float* __restrict__ adst, float* __restrict__ h2,
    float* __restrict__ ssrc, float* __restrict__ sdst) {
  int tid = threadIdx.x;
  int lane6 = tid & 63;
  int c0 = lane6 * 4;              // 4 output cols per thread
  int hh = lane6 >> 4;             // head of this 16-lane group
  int rbase = (tid >> 6) * 2;      // 2 rows per thread
  float4 acc0 = make_float4(0.f, 0.f, 0.f, 0.f);
  float4 acc1 = make_float4(0.f, 0.f, 0.f, 0.f);
#pragma unroll
  for (int kq = 0; kq < 16; ++kq) {
    const float* Wk = W + kq * 4 * 256 + c0;
    float4 w0 = *(const float4*)(Wk);
    float4 w1 = *(const float4*)(Wk + 256);
    float4 w2 = *(const float4*)(Wk + 512);
    float4 w3 = *(const float4*)(Wk + 768);
    float4 x0 = *(const float4*)(&xs[rbase][kq * 4]);
    float4 x1 = *(const float4*)(&xs[rbase + 1][kq * 4]);
    fma4(acc0, x0.x, w0); fma4(acc0, x0.y, w1); fma4(acc0, x0.z, w2); fma4(acc0, x0.w, w3);
    fma4(acc1, x1.x, w0); fma4(acc1, x1.y, w1); fma4(acc1, x1.z, w2); fma4(acc1, x1.w, w3);
  }
  float4 av = *(const float4*)(asrc + c0);
  float4 bv = *(const float4*)(adst + c0);
#pragma unroll
  for (int r = 0; r < 2; ++r) {
    float4 a = (r == 0) ? acc0 : acc1;
    int row = r0 + rbase + r;
    *(float4*)(h2 + row * 256 + c0) = a;
    float ps = a.x * av.x + a.y * av.y + a.z * av.z + a.w * av.w;
    float pd = a.x * bv.x + a.y * bv.y + a.z * bv.z + a.w * bv.w;
#pragma unroll
    for (int off = 8; off > 0; off >>= 1) {
      ps += __shfl_down(ps, off);
      pd += __shfl_down(pd, off);
    }
    if ((lane6 & 15) == 0) {
      ssrc[hh * N + row] = ps;
      sdst[hh * N + row] = pd;
    }
  }
}

// ---------- layer1: encoder (relu(x@Wenc+benc)) fused with proj ----------
__global__ __launch_bounds__(256) void k_encproj(const float* __restrict__ x,
    const float* __restrict__ Wenc, const float* __restrict__ benc,
    const float* __restrict__ W, const float* __restrict__ asrc,
    const float* __restrict__ adst, float* __restrict__ h2,
    float* __restrict__ ssrc, float* __restrict__ sdst) {
  __shared__ float xs[8][64];
  int tid = threadIdx.x;
  int r0 = blockIdx.x * 8;
  {
    int row = tid >> 5;            // 0..7
    int c = (tid & 31) * 2;        // 0..62
    const float* xr = x + (r0 + row) * 64;
    float a0 = benc[c], a1 = benc[c + 1];
#pragma unroll
    for (int k = 0; k < 64; ++k) {
      float xv = xr[k];
      float2 w = *(const float2*)(Wenc + k * 64 + c);
      a0 = fmaf(xv, w.x, a0);
      a1 = fmaf(xv, w.y, a1);
    }
    xs[row][c] = fmaxf(a0, 0.f);
    xs[row][c + 1] = fmaxf(a1, 0.f);
  }
  __syncthreads();
  proj_body(xs, r0, W, asrc, adst, h2, ssrc, sdst);
}

// ---------- layer2 proj: stage hin rows then proj ----------
__global__ __launch_bounds__(256) void k_proj(const float* __restrict__ hin,
    const float* __restrict__ W, const float* __restrict__ asrc,
    const float* __restrict__ adst, float* __restrict__ h2,
    float* __restrict__ ssrc, float* __restrict__ sdst) {
  __shared__ float xs[8][64];
  int tid = threadIdx.x;
  int r0 = blockIdx.x * 8;
  if (tid < 128) ((float4*)xs)[tid] = ((const float4*)(hin + r0 * 64))[tid];
  __syncthreads();
  proj_body(xs, r0, W, asrc, adst, h2, ssrc, sdst);
}

// ---------- rank, stage 1: partial counts over j-chunks (per-lane LDS scan) ----------
// grid (H*16, RCHUNK); block 256. Deterministic, no atomics.
__global__ __launch_bounds__(256) void k_rank_part(const float* __restrict__ ssrc,
                                                   int* __restrict__ partial) { // [RCHUNK][H][N]
    __shared__ __align__(16) float vs[RJ];
    int h = blockIdx.x >> 4, bi = blockIdx.x & 15;
    int c = blockIdx.y;
    int tid = threadIdx.x;
    vs[tid] = ssrc[h * N + c * RJ + tid];
    __syncthreads();
    int i = bi * 256 + tid;
    float vi = ssrc[h * N + i];
    int jbase = c * RJ;
    int rank = 0;
    const float4* vs4 = (const float4*)vs;
#pragma unroll 4
    for (int j4 = 0; j4 < RJ / 4; ++j4) {
        float4 q = vs4[j4];
        int jb = jbase + (j4 << 2);
        rank += (q.x < vi || (q.x == vi && jb < i));
        rank += (q.y < vi || (q.y == vi && jb + 1 < i));
        rank += (q.z < vi || (q.z == vi && jb + 2 < i));
        rank += (q.w < vi || (q.w == vi && jb + 3 < i));
    }
    partial[(c * H + h) * N + i] = rank;
}

// ---------- rank, stage 2: reduce partials + scatter ----------
__global__ __launch_bounds__(256) void k_rank_reduce(const float* __restrict__ ssrc,
                                                     const int* __restrict__ partial,
                                                     float* __restrict__ srtv,
                                                     int* __restrict__ srti) {
    int h = blockIdx.x >> 4, bi = blockIdx.x & 15;
    int i = bi * 256 + threadIdx.x;
    int rank = 0;
#pragma unroll
    for (int c = 0; c < RCHUNK; ++c) rank += partial[(c * H + h) * N + i];
    srtv[h * N + rank] = ssrc[h * N + i];
    srti[h * N + rank] = i;
}

// ---------- S1: per-chunk totals + weight arrays (exp from srtv) ----------
__global__ __launch_bounds__(128) void k_s1(const float* __restrict__ h2,
                                            const int* __restrict__ srti,
                                            const float* __restrict__ srtv,
                                            float* __restrict__ wA, float* __restrict__ wB,
                                            float* __restrict__ TA, float* __restrict__ TB) {
    int h = blockIdx.x >> 6, c = blockIdx.x & 63, col = threadIdx.x;
    __shared__ int pj[64];
    __shared__ float wa[64], wb[64];
    int j0 = c * 64;
    float m1 = srtv[h * N + N - 1];
    if (col < 64) {
        int j = j0 + col;
        pj[col] = srti[h * N + j];
        float sv = srtv[h * N + j];
        float a = expf(sv - m1);
        float b = expf(0.2f * (sv - m1));
        wa[col] = a; wb[col] = b;
        wA[h * N + j] = a; wB[h * N + j] = b;
    }
    __syncthreads();
    if (col >= 65) return;
    float accA = 0.f, accB = 0.f;
#pragma unroll 8
    for (int j = 0; j < 64; ++j) {
        float val = (col < 64) ? h2[pj[j] * HD + h * 64 + col] : 1.0f;
        accA = fmaf(wa[j], val, accA);
        accB = fmaf(wb[j], val, accB);
    }
    TA[(h * 64 + c) * TS + col] = accA;
    TB[(h * 64 + c) * TS + col] = accB;
}

// ---------- S3: self-computed offsets + full suffix/prefix tables ----------
__global__ __launch_bounds__(128) void k_s3(const float* __restrict__ h2,
                                            const int* __restrict__ srti,
                                            const float* __restrict__ wA, const float* __restrict__ wB,
                                            const float* __restrict__ TA, const float* __restrict__ TB,
                                            float* __restrict__ SA, float* __restrict__ PB) {
    int h = blockIdx.x >> 6, c = blockIdx.x & 63, col = threadIdx.x;
    __shared__ int pj[64];
    __shared__ float wa[64], wb[64];
    int j0 = c * 64;
    if (col < 64) {
        pj[col] = srti[h * N + j0 + col];
        wa[col] = wA[h * N + j0 + col];
        wb[col] = wB[h * N + j0 + col];
    }
    __syncthreads();
    if (col >= 65) return;
    float offA = 0.f, offB = 0.f;
    for (int cc = c + 1; cc < 64; ++cc) offA += TA[(h * 64 + cc) * TS + col];
    for (int cc = 0; cc < c; ++cc)      offB += TB[(h * 64 + cc) * TS + col];
    float v[64];
#pragma unroll
    for (int j = 0; j < 64; ++j)
        v[j] = (col < 64) ? h2[pj[j] * HD + h * 64 + col] : 1.0f;
    float acc = offA;
#pragma unroll
    for (int j = 63; j >= 0; --j) {  // SA[i] = sum_{j>=i} wA_j * v_j
        acc = fmaf(wa[j], v[j], acc);
        SA[(size_t)(h * (N + 1) + j0 + j) * TS + col] = acc;
    }
    acc = offB;
#pragma unroll
    for (int j = 0; j < 64; ++j) {   // PB[i] = sum_{j<i} wB_j * v_j
        acc = fmaf(wb[j], v[j], acc);
        PB[(size_t)(h * (N + 1) + j0 + j + 1) * TS + col] = acc;
    }
    if (c == 63) SA[(size_t)(h * (N + 1) + N) * TS + col] = 0.f;
    if (c == 0)  PB[(size_t)(h * (N + 1) + 0) * TS + col] = 0.f;
}

// ---------- target: blend tables per (t,h); MODE1 fuses output heads ----------
template <int MODE>
__global__ __launch_bounds__(256) void k_target_t(const float* __restrict__ sdst,
                                                  const float* __restrict__ srtv,
                                                  const float* __restrict__ SA,
                                                  const float* __restrict__ PB,
                                                  const float* __restrict__ bias,
                                                  float* __restrict__ hout,
                                                  const float* __restrict__ Wact,
                                                  const float* __restrict__ bact,
                                                  const float* __restrict__ Wcri,
                                                  const float* __restrict__ bcri,
                                                  float* __restrict__ out) {
    __shared__ float bnd[4][64];
    int tid = threadIdx.x;
    { int hh = tid >> 6, l = tid & 63; bnd[hh][l] = srtv[hh * N + l * 64]; }
    __syncthreads();
    int t = blockIdx.x * 4 + (tid >> 6);
    int lane = tid & 63;
    float acc = 0.f;
#pragma unroll
    for (int h = 0; h < H; ++h) {
        const float* sv = srtv + h * N;
        float dst = sdst[h * N + t];
        float thr = -dst;
        float m1 = sv[N - 1];
        unsigned long long b1 = __ballot(bnd[h][lane] <= thr);
        int c1 = __popcll(b1);
        int seg = c1 > 0 ? c1 - 1 : 0;
        unsigned long long b2 = __ballot(sv[seg * 64 + lane] <= thr);
        int k = seg * 64 + __popcll(b2);
        float u = dst + m1;
        float g = fmaxf(u, 0.2f * u);          // keeps both exps <= 1
        float wAt = expf(u - g);
        float wBt = expf(0.2f * u - g);
        const float* sa = SA + (size_t)(h * (N + 1) + k) * TS;
        const float* pb = PB + (size_t)(h * (N + 1) + k) * TS;
        float num = wAt * sa[lane] + wBt * pb[lane];
        float den = wAt * sa[64] + wBt * pb[64];
        acc += num / den;
    }
    float hv = fmaxf(acc * 0.25f + bias[lane], 0.f);
    if constexpr (MODE == 0) {
        hout[t * 64 + lane] = hv;
    } else {
        float p0 = hv * Wact[lane * 2 + 0];
        float p1 = hv * Wact[lane * 2 + 1];
        float p2 = hv * Wcri[lane];
#pragma unroll
        for (int off = 32; off > 0; off >>= 1) {
            p0 += __shfl_down(p0, off);
            p1 += __shfl_down(p1, off);
            p2 += __shfl_down(p2, off);
        }
        if (lane == 0) {
            float l0 = fminf(fmaxf(p0 + bact[0], -5.f), 5.f);
            float l1 = fminf(fmaxf(p1 + bact[1], -5.f), 5.f);
            out[t * 2 + 0] = l0;
            out[t * 2 + 1] = fabsf(l1);
            out[2 * N + t] = p2 + bcri[0];
        }
    }
}

extern "C" void kernel_launch(void* const* d_in, const int* in_sizes, int n_in,
                              void* d_out, int out_size, void* d_ws, size_t ws_size,
                              hipStream_t stream) {
    (void)in_sizes; (void)n_in; (void)out_size; (void)ws_size;
    const float* x     = (const float*)d_in[0];
    const float* W_enc = (const float*)d_in[1];
    const float* b_enc = (const float*)d_in[2];
    const float* W1    = (const float*)d_in[3];
    const float* as1   = (const float*)d_in[4];
    const float* ad1   = (const float*)d_in[5];
    const float* b1    = (const float*)d_in[6];
    const float* W2    = (const float*)d_in[7];
    const float* as2   = (const float*)d_in[8];
    const float* ad2   = (const float*)d_in[9];
    const float* b2    = (const float*)d_in[10];
    const float* W_act = (const float*)d_in[11];
    const float* b_act = (const float*)d_in[12];
    const float* W_cri = (const float*)d_in[13];
    const float* b_cri = (const float*)d_in[14];
    float* out = (float*)d_out;

    float* p = (float*)d_ws;
    float* h2   = p; p += N * HD;
    float* hA   = p; p += N * D;
    float* ssrc = p; p += H * N;
    float* sdst = p; p += H * N;
    float* srtv = p; p += H * N;
    int*   srti = (int*)p; p += H * N;
    float* wA   = p; p += H * N;
    float* wB   = p; p += H * N;
    float* TA   = p; p += H * 64 * TS;
    float* TB   = p; p += H * 64 * TS;
    float* SA   = p; p += (size_t)H * (N + 1) * TS;
    float* PB   = p; p += (size_t)H * (N + 1) * TS;
    int*   rpart = (int*)p; p += RCHUNK * H * N;

    dim3 rp_grid(H * 16, RCHUNK);

    // layer 1 (encoder fused into proj)
    k_encproj<<<N / 8, 256, 0, stream>>>(x, W_enc, b_enc, W1, as1, ad1, h2, ssrc, sdst);
    k_rank_part<<<rp_grid, 256, 0, stream>>>(ssrc, rpart);
    k_rank_reduce<<<H * 16, 256, 0, stream>>>(ssrc, rpart, srtv, srti);
    k_s1<<<H * 64, 128, 0, stream>>>(h2, srti, srtv, wA, wB, TA, TB);
    k_s3<<<H * 64, 128, 0, stream>>>(h2, srti, wA, wB, TA, TB, SA, PB);
    k_target_t<0><<<N / 4, 256, 0, stream>>>(sdst, srtv, SA, PB, b1, hA,
                                             nullptr, nullptr, nullptr, nullptr, nullptr);

    // layer 2 (heads fused into target)
    k_proj<<<N / 8, 256, 0, stream>>>(hA, W2, as2, ad2, h2, ssrc, sdst);
    k_rank_part<<<rp_grid, 256, 0, stream>>>(ssrc, rpart);
    k_rank_reduce<<<H * 16, 256, 0, stream>>>(ssrc, rpart, srtv, srti);
    k_s1<<<H * 64, 128, 0, stream>>>(h2, srti, srtv, wA, wB, TA, TB);
    k_s3<<<H * 64, 128, 0, stream>>>(h2, srti, wA, wB, TA, TB, SA, PB);
    k_target_t<1><<<N / 4, 256, 0, stream>>>(sdst, srtv, SA, PB, b2, nullptr,
                                             W_act, b_act, W_cri, b_cri, out);
}